// Round 1
// baseline (94.808 us; speedup 1.0000x reference)
//
#include <hip/hip_runtime.h>
#include <math.h>

// FinalGNN: b=16, n=256, feature=64
// ws layout (floats):
//   h      : [16][256][64]   row-major        262144
//   hT     : [16][64][256]                    262144
//   a_i    : [16][256][64]   (includes s_b1)  262144
//   a_jT   : [16][64][256]                    262144
//   sq     : [16][256]                          4096
//   h_agg  : [16][256][64]                    262144
//   h_res  : [16][256][64]                    262144

#define OFF_H      0
#define OFF_HT     262144
#define OFF_AI     (262144*2)
#define OFF_AJT    (262144*3)
#define OFF_SQ     (262144*4)
#define OFF_HAGG   (262144*4 + 4096)
#define OFF_HRES   (262144*5 + 4096)

__device__ __forceinline__ float elu_f(float x) { return x > 0.f ? x : expm1f(x); }

// K1: h = elu(x@proj_w + proj_b); a_i = h@s_w1[:64] + s_b1; a_j = h@s_w1[64:]; sq = sum(h*h)
// 1024 blocks x 256 threads; one wave (64 lanes) per row.
__global__ __launch_bounds__(256) void k1_embed(
    const float* __restrict__ x,
    const float* __restrict__ proj_w, const float* __restrict__ proj_b,
    const float* __restrict__ s_w1, const float* __restrict__ s_b1,
    float* __restrict__ h, float* __restrict__ hT,
    float* __restrict__ a_i, float* __restrict__ a_jT,
    float* __restrict__ sq)
{
    int lane = threadIdx.x & 63;
    int wave = threadIdx.x >> 6;
    int row  = blockIdx.x * 4 + wave;      // [0, 4096) = b*256 + i
    int b = row >> 8, i = row & 255;

    __shared__ float hsh[4][64];

    float x0 = x[row*4+0], x1 = x[row*4+1], x2 = x[row*4+2], x3 = x[row*4+3];
    float hv = x0*proj_w[lane] + x1*proj_w[64+lane] + x2*proj_w[128+lane]
             + x3*proj_w[192+lane] + proj_b[lane];
    hv = elu_f(hv);
    hsh[wave][lane] = hv;
    __syncthreads();

    float ai = s_b1[lane], aj = 0.f, sqv = 0.f;
    #pragma unroll
    for (int e = 0; e < 64; ++e) {
        float he = hsh[wave][e];
        ai  += he * s_w1[e*64 + lane];
        aj  += he * s_w1[(64+e)*64 + lane];
        sqv += he * he;
    }
    h[row*64 + lane] = hv;
    hT[b*64*256 + lane*256 + i] = hv;
    a_i[row*64 + lane] = ai;
    a_jT[b*64*256 + lane*256 + i] = aj;
    if (lane == 0) sq[row] = sqv;
}

// K2: per (b,i): for each j: LN(pre)->relu->dot->softplus->sigma; d2 via gram; adj;
//     then h_agg[b,i,:] = sum_j adj * h[b,j,:].  4096 blocks x 256 threads (thread = j).
__global__ __launch_bounds__(256) void k2_pair(
    const float* __restrict__ a_i, const float* __restrict__ a_jT,
    const float* __restrict__ hT, const float* __restrict__ h,
    const float* __restrict__ sq,
    const float* __restrict__ ln_g, const float* __restrict__ ln_b,
    const float* __restrict__ s_w2, const float* __restrict__ s_b2,
    float* __restrict__ h_agg)
{
    int bi = blockIdx.x;               // b*256 + i
    int b = bi >> 8;
    int j = threadIdx.x;

    __shared__ float ai_sh[64], hi_sh[64], g_sh[64], be_sh[64], w2_sh[64];
    __shared__ float adj_sh[256];
    __shared__ float part_sh[256];

    if (j < 64) {
        ai_sh[j] = a_i[bi*64 + j];
        hi_sh[j] = h[bi*64 + j];
        g_sh[j]  = ln_g[j];
        be_sh[j] = ln_b[j];
        w2_sh[j] = s_w2[j];
    }
    __syncthreads();

    const float* ajb = a_jT + b*64*256;
    const float* htb = hT  + b*64*256;

    float pre_r[64];
    float s = 0.f, ssum = 0.f, dot = 0.f;
    #pragma unroll
    for (int d = 0; d < 64; ++d) {
        float ajd = ajb[d*256 + j];     // coalesced across lanes
        float hjd = htb[d*256 + j];     // coalesced across lanes
        float pre = ai_sh[d] + ajd;
        pre_r[d] = pre;
        s    += pre;
        ssum += pre * pre;
        dot  += hi_sh[d] * hjd;
    }
    float mu  = s * (1.f/64.f);
    float var = ssum * (1.f/64.f) - mu*mu;
    float rs  = rsqrtf(var + 1e-5f);

    float acc = 0.f;
    #pragma unroll
    for (int d = 0; d < 64; ++d) {
        float t = (pre_r[d] - mu) * rs * g_sh[d] + be_sh[d];
        t = fmaxf(t, 0.f);
        acc += t * w2_sh[d];
    }
    float sp  = acc + s_b2[0];
    // softplus, stable
    float sig = fmaxf(sp, 0.f) + log1pf(expf(-fabsf(sp)));

    float sqi = sq[bi];
    float sqj = sq[b*256 + j];
    float d2  = fmaxf(sqi + sqj - 2.f*dot, 0.f);
    float adj = expf(-d2 / (2.f*sig*sig + 1e-6f));

    adj_sh[j] = adj;
    __syncthreads();

    // aggregation: h_agg[b,i,d] = sum_j adj[j] * h[b,j,d]
    int d = threadIdx.x & 63, q = threadIdx.x >> 6;
    const float* hb = h + b*256*64;
    float part = 0.f;
    #pragma unroll 8
    for (int k = 0; k < 64; ++k) {
        int jj = q*64 + k;
        part += adj_sh[jj] * hb[jj*64 + d];   // coalesced across lanes (d)
    }
    part_sh[threadIdx.x] = part;
    __syncthreads();
    if (threadIdx.x < 64) {
        float v = part_sh[threadIdx.x] + part_sh[64+threadIdx.x]
                + part_sh[128+threadIdx.x] + part_sh[192+threadIdx.x];
        h_agg[bi*64 + threadIdx.x] = v;
    }
}

// K3: h_res = elu(h_agg @ gnn_w + h).  1024 blocks x 256 threads; wave per row.
__global__ __launch_bounds__(256) void k3_gnn(
    const float* __restrict__ h_agg, const float* __restrict__ h,
    const float* __restrict__ gnn_w, float* __restrict__ h_res)
{
    int lane = threadIdx.x & 63, wave = threadIdx.x >> 6;
    int row = blockIdx.x*4 + wave;
    __shared__ float agg_sh[4][64];
    agg_sh[wave][lane] = h_agg[row*64 + lane];
    __syncthreads();
    float acc = 0.f;
    #pragma unroll
    for (int e = 0; e < 64; ++e)
        acc += agg_sh[wave][e] * gnn_w[e*64 + lane];
    float v = elu_f(acc + h[row*64 + lane]);
    h_res[row*64 + lane] = v;
}

// K4: pooled = [mean_i, max_i]; classifier.  16 blocks x 256 threads.
__global__ __launch_bounds__(256) void k4_pool_cls(
    const float* __restrict__ h_res,
    const float* __restrict__ c_w1, const float* __restrict__ c_b1,
    const float* __restrict__ bn_g, const float* __restrict__ bn_b,
    const float* __restrict__ bn_mean, const float* __restrict__ bn_var,
    const float* __restrict__ c_w2, const float* __restrict__ c_b2,
    float* __restrict__ out)
{
    int b = blockIdx.x;
    int tid = threadIdx.x;
    int d = tid & 63, q = tid >> 6;
    const float* hb = h_res + b*256*64;

    float sum = 0.f, mx = -INFINITY;
    #pragma unroll 8
    for (int k = 0; k < 64; ++k) {
        float v = hb[(q*64+k)*64 + d];
        sum += v; mx = fmaxf(mx, v);
    }
    __shared__ float sum_sh[256], max_sh[256];
    __shared__ float pm_sh[64], px_sh[64];
    sum_sh[tid] = sum; max_sh[tid] = mx;
    __syncthreads();
    if (tid < 64) {
        float tsum = sum_sh[tid] + sum_sh[64+tid] + sum_sh[128+tid] + sum_sh[192+tid];
        float tmax = fmaxf(fmaxf(max_sh[tid], max_sh[64+tid]),
                           fmaxf(max_sh[128+tid], max_sh[192+tid]));
        pm_sh[tid] = tsum * (1.f/256.f);
        px_sh[tid] = tmax;
    }
    __syncthreads();
    if (tid < 64) {
        float acc = c_b1[tid];
        #pragma unroll
        for (int e = 0; e < 64; ++e) {
            acc += pm_sh[e] * c_w1[e*64 + tid];
            acc += px_sh[e] * c_w1[(64+e)*64 + tid];
        }
        float z = (acc - bn_mean[tid]) * rsqrtf(bn_var[tid] + 1e-5f) * bn_g[tid] + bn_b[tid];
        z = elu_f(z);
        float c0 = z * c_w2[tid*2 + 0];
        float c1 = z * c_w2[tid*2 + 1];
        for (int off = 32; off > 0; off >>= 1) {
            c0 += __shfl_down(c0, off);
            c1 += __shfl_down(c1, off);
        }
        if (tid == 0) {
            out[b*2 + 0] = c0 + c_b2[0];
            out[b*2 + 1] = c1 + c_b2[1];
        }
    }
}

extern "C" void kernel_launch(void* const* d_in, const int* in_sizes, int n_in,
                              void* d_out, int out_size, void* d_ws, size_t ws_size,
                              hipStream_t stream) {
    const float* x       = (const float*)d_in[0];
    const float* proj_w  = (const float*)d_in[1];
    const float* proj_b  = (const float*)d_in[2];
    const float* s_w1    = (const float*)d_in[3];
    const float* s_b1    = (const float*)d_in[4];
    const float* ln_g    = (const float*)d_in[5];
    const float* ln_b    = (const float*)d_in[6];
    const float* s_w2    = (const float*)d_in[7];
    const float* s_b2    = (const float*)d_in[8];
    const float* gnn_w   = (const float*)d_in[9];
    const float* c_w1    = (const float*)d_in[10];
    const float* c_b1    = (const float*)d_in[11];
    const float* bn_g    = (const float*)d_in[12];
    const float* bn_b    = (const float*)d_in[13];
    const float* bn_mean = (const float*)d_in[14];
    const float* bn_var  = (const float*)d_in[15];
    const float* c_w2    = (const float*)d_in[16];
    const float* c_b2    = (const float*)d_in[17];

    float* w = (float*)d_ws;
    float* h     = w + OFF_H;
    float* hT    = w + OFF_HT;
    float* a_i   = w + OFF_AI;
    float* a_jT  = w + OFF_AJT;
    float* sq    = w + OFF_SQ;
    float* h_agg = w + OFF_HAGG;
    float* h_res = w + OFF_HRES;
    float* out   = (float*)d_out;

    k1_embed<<<1024, 256, 0, stream>>>(x, proj_w, proj_b, s_w1, s_b1,
                                       h, hT, a_i, a_jT, sq);
    k2_pair<<<4096, 256, 0, stream>>>(a_i, a_jT, hT, h, sq,
                                      ln_g, ln_b, s_w2, s_b2, h_agg);
    k3_gnn<<<1024, 256, 0, stream>>>(h_agg, h, gnn_w, h_res);
    k4_pool_cls<<<16, 256, 0, stream>>>(h_res, c_w1, c_b1, bn_g, bn_b,
                                        bn_mean, bn_var, c_w2, c_b2, out);
}

// Round 2
// 52.464 us; speedup vs baseline: 1.8071x; 1.8071x over previous
//
#include <hip/hip_runtime.h>
#include <math.h>

// FinalGNN: b=16, n=256, feature=64
// ws layout (floats):
//   h      : [16][256][64]   row-major        262144
//   hT     : [16][64][256]                    262144
//   a_i    : [16][256][64]   (includes s_b1)  262144
//   a_jT   : [16][64][256]                    262144
//   sq     : [16][256]                          4096
//   h_agg  : [16][256][64]                    262144
//   h_res  : [16][256][64]                    262144

#define OFF_H      0
#define OFF_HT     262144
#define OFF_AI     (262144*2)
#define OFF_AJT    (262144*3)
#define OFF_SQ     (262144*4)
#define OFF_HAGG   (262144*4 + 4096)
#define OFF_HRES   (262144*5 + 4096)

__device__ __forceinline__ float elu_f(float x) { return x > 0.f ? x : expm1f(x); }

// K1: h = elu(x@proj_w + proj_b); a_i = h@s_w1[:64] + s_b1; a_j = h@s_w1[64:]; sq = sum(h*h)
// 1024 blocks x 256 threads; one wave (64 lanes) per row.
__global__ __launch_bounds__(256) void k1_embed(
    const float* __restrict__ x,
    const float* __restrict__ proj_w, const float* __restrict__ proj_b,
    const float* __restrict__ s_w1, const float* __restrict__ s_b1,
    float* __restrict__ h, float* __restrict__ hT,
    float* __restrict__ a_i, float* __restrict__ a_jT,
    float* __restrict__ sq)
{
    int lane = threadIdx.x & 63;
    int wave = threadIdx.x >> 6;
    int row  = blockIdx.x * 4 + wave;      // [0, 4096) = b*256 + i
    int b = row >> 8, i = row & 255;

    __shared__ float hsh[4][64];

    float x0 = x[row*4+0], x1 = x[row*4+1], x2 = x[row*4+2], x3 = x[row*4+3];
    float hv = x0*proj_w[lane] + x1*proj_w[64+lane] + x2*proj_w[128+lane]
             + x3*proj_w[192+lane] + proj_b[lane];
    hv = elu_f(hv);
    hsh[wave][lane] = hv;
    __syncthreads();

    float ai = s_b1[lane], aj = 0.f, sqv = 0.f;
    #pragma unroll
    for (int e = 0; e < 64; ++e) {
        float he = hsh[wave][e];
        ai  += he * s_w1[e*64 + lane];
        aj  += he * s_w1[(64+e)*64 + lane];
        sqv += he * he;
    }
    h[row*64 + lane] = hv;
    hT[b*64*256 + lane*256 + i] = hv;
    a_i[row*64 + lane] = ai;
    a_jT[b*64*256 + lane*256 + i] = aj;
    if (lane == 0) sq[row] = sqv;
}

// K2: per block: one b, TI=4 consecutive i rows; thread = j in [0,256).
// Pass 1: stats (sum pre, sum pre^2) + dot(h_i,h_j) for all 4 i (shared a_jT/hT loads).
// Pass 2: reload a_jT, apply LN->relu->dot(w2).
// Then sigma/softplus, adj, and adj @ h aggregation.
#define TI 4
__global__ __launch_bounds__(256) void k2_pair(
    const float* __restrict__ a_i, const float* __restrict__ a_jT,
    const float* __restrict__ hT, const float* __restrict__ h,
    const float* __restrict__ sq,
    const float* __restrict__ ln_g, const float* __restrict__ ln_b,
    const float* __restrict__ s_w2, const float* __restrict__ s_b2,
    float* __restrict__ h_agg)
{
    int bi0 = blockIdx.x * TI;         // first row (b*256 + i0), TI divides 256
    int b   = bi0 >> 8;
    int j   = threadIdx.x;

    __shared__ float ai_sh[TI][64], hi_sh[TI][64];
    __shared__ float g_sh[64], be_sh[64], w2_sh[64];
    __shared__ float adj_sh[256][TI];            // [j][i], float4-readable
    __shared__ float part_sh[4][TI][64];

    if (j < 64) { g_sh[j] = ln_g[j]; be_sh[j] = ln_b[j]; w2_sh[j] = s_w2[j]; }
    {
        int i = j >> 6, d = j & 63;
        ai_sh[i][d] = a_i[(bi0 + i)*64 + d];
        hi_sh[i][d] = h[(bi0 + i)*64 + d];
    }
    __syncthreads();

    const float* ajb = a_jT + b*64*256;
    const float* htb = hT   + b*64*256;

    // ---- pass 1: stats + gram dot ----
    float ps[TI], pss[TI], dt[TI];
    #pragma unroll
    for (int i = 0; i < TI; ++i) { ps[i] = 0.f; pss[i] = 0.f; dt[i] = 0.f; }
    #pragma unroll 8
    for (int d = 0; d < 64; ++d) {
        float ajd = ajb[d*256 + j];
        float hjd = htb[d*256 + j];
        #pragma unroll
        for (int i = 0; i < TI; ++i) {
            float pre = ai_sh[i][d] + ajd;
            ps[i]  += pre;
            pss[i]  = fmaf(pre, pre, pss[i]);
            dt[i]   = fmaf(hi_sh[i][d], hjd, dt[i]);
        }
    }
    float rs[TI], nmurs[TI];
    #pragma unroll
    for (int i = 0; i < TI; ++i) {
        float mu  = ps[i] * (1.f/64.f);
        float var = pss[i] * (1.f/64.f) - mu*mu;
        rs[i]    = rsqrtf(var + 1e-5f);
        nmurs[i] = -mu * rs[i];
    }

    // ---- pass 2: LN -> relu -> dot(w2) ----
    float acc[TI];
    #pragma unroll
    for (int i = 0; i < TI; ++i) acc[i] = 0.f;
    #pragma unroll 8
    for (int d = 0; d < 64; ++d) {
        float ajd = ajb[d*256 + j];
        float gd = g_sh[d], bd = be_sh[d], wd = w2_sh[d];
        #pragma unroll
        for (int i = 0; i < TI; ++i) {
            float pre = ai_sh[i][d] + ajd;
            float v   = fmaf(pre, rs[i], nmurs[i]);
            float t   = fmaf(v, gd, bd);
            t = fmaxf(t, 0.f);
            acc[i] = fmaf(t, wd, acc[i]);
        }
    }

    // ---- sigma, adj ----
    float b2  = s_b2[0];
    float sqj = sq[b*256 + j];
    #pragma unroll
    for (int i = 0; i < TI; ++i) {
        float sp  = acc[i] + b2;
        float sig = fmaxf(sp, 0.f) + log1pf(expf(-fabsf(sp)));   // softplus
        float sqi = sq[bi0 + i];
        float d2  = fmaxf(sqi + sqj - 2.f*dt[i], 0.f);
        adj_sh[j][i] = expf(-d2 / (2.f*sig*sig + 1e-6f));
    }
    __syncthreads();

    // ---- aggregation: h_agg[b,i,d] = sum_j adj[i,j] * h[b,j,d] ----
    int d = j & 63, q = j >> 6;
    const float* hb = h + b*256*64;
    float part[TI];
    #pragma unroll
    for (int i = 0; i < TI; ++i) part[i] = 0.f;
    #pragma unroll 8
    for (int k = 0; k < 64; ++k) {
        int jj = q*64 + k;
        float hv = hb[jj*64 + d];                         // coalesced (lanes=d)
        float4 a4 = *(const float4*)&adj_sh[jj][0];       // LDS broadcast (uniform addr)
        part[0] = fmaf(a4.x, hv, part[0]);
        part[1] = fmaf(a4.y, hv, part[1]);
        part[2] = fmaf(a4.z, hv, part[2]);
        part[3] = fmaf(a4.w, hv, part[3]);
    }
    #pragma unroll
    for (int i = 0; i < TI; ++i) part_sh[q][i][d] = part[i];
    __syncthreads();
    {
        int i = j >> 6, dd = j & 63;
        float v = part_sh[0][i][dd] + part_sh[1][i][dd]
                + part_sh[2][i][dd] + part_sh[3][i][dd];
        h_agg[(bi0 + i)*64 + dd] = v;
    }
}

// K3: h_res = elu(h_agg @ gnn_w + h).  1024 blocks x 256 threads; wave per row.
__global__ __launch_bounds__(256) void k3_gnn(
    const float* __restrict__ h_agg, const float* __restrict__ h,
    const float* __restrict__ gnn_w, float* __restrict__ h_res)
{
    int lane = threadIdx.x & 63, wave = threadIdx.x >> 6;
    int row = blockIdx.x*4 + wave;
    __shared__ float agg_sh[4][64];
    agg_sh[wave][lane] = h_agg[row*64 + lane];
    __syncthreads();
    float acc = 0.f;
    #pragma unroll
    for (int e = 0; e < 64; ++e)
        acc += agg_sh[wave][e] * gnn_w[e*64 + lane];
    float v = elu_f(acc + h[row*64 + lane]);
    h_res[row*64 + lane] = v;
}

// K4: pooled = [mean_i, max_i]; classifier.  16 blocks x 256 threads.
__global__ __launch_bounds__(256) void k4_pool_cls(
    const float* __restrict__ h_res,
    const float* __restrict__ c_w1, const float* __restrict__ c_b1,
    const float* __restrict__ bn_g, const float* __restrict__ bn_b,
    const float* __restrict__ bn_mean, const float* __restrict__ bn_var,
    const float* __restrict__ c_w2, const float* __restrict__ c_b2,
    float* __restrict__ out)
{
    int b = blockIdx.x;
    int tid = threadIdx.x;
    int d = tid & 63, q = tid >> 6;
    const float* hb = h_res + b*256*64;

    float sum = 0.f, mx = -INFINITY;
    #pragma unroll 8
    for (int k = 0; k < 64; ++k) {
        float v = hb[(q*64+k)*64 + d];
        sum += v; mx = fmaxf(mx, v);
    }
    __shared__ float sum_sh[256], max_sh[256];
    __shared__ float pm_sh[64], px_sh[64];
    sum_sh[tid] = sum; max_sh[tid] = mx;
    __syncthreads();
    if (tid < 64) {
        float tsum = sum_sh[tid] + sum_sh[64+tid] + sum_sh[128+tid] + sum_sh[192+tid];
        float tmax = fmaxf(fmaxf(max_sh[tid], max_sh[64+tid]),
                           fmaxf(max_sh[128+tid], max_sh[192+tid]));
        pm_sh[tid] = tsum * (1.f/256.f);
        px_sh[tid] = tmax;
    }
    __syncthreads();
    if (tid < 64) {
        float acc = c_b1[tid];
        #pragma unroll
        for (int e = 0; e < 64; ++e) {
            acc += pm_sh[e] * c_w1[e*64 + tid];
            acc += px_sh[e] * c_w1[(64+e)*64 + tid];
        }
        float z = (acc - bn_mean[tid]) * rsqrtf(bn_var[tid] + 1e-5f) * bn_g[tid] + bn_b[tid];
        z = elu_f(z);
        float c0 = z * c_w2[tid*2 + 0];
        float c1 = z * c_w2[tid*2 + 1];
        for (int off = 32; off > 0; off >>= 1) {
            c0 += __shfl_down(c0, off);
            c1 += __shfl_down(c1, off);
        }
        if (tid == 0) {
            out[b*2 + 0] = c0 + c_b2[0];
            out[b*2 + 1] = c1 + c_b2[1];
        }
    }
}

extern "C" void kernel_launch(void* const* d_in, const int* in_sizes, int n_in,
                              void* d_out, int out_size, void* d_ws, size_t ws_size,
                              hipStream_t stream) {
    const float* x       = (const float*)d_in[0];
    const float* proj_w  = (const float*)d_in[1];
    const float* proj_b  = (const float*)d_in[2];
    const float* s_w1    = (const float*)d_in[3];
    const float* s_b1    = (const float*)d_in[4];
    const float* ln_g    = (const float*)d_in[5];
    const float* ln_b    = (const float*)d_in[6];
    const float* s_w2    = (const float*)d_in[7];
    const float* s_b2    = (const float*)d_in[8];
    const float* gnn_w   = (const float*)d_in[9];
    const float* c_w1    = (const float*)d_in[10];
    const float* c_b1    = (const float*)d_in[11];
    const float* bn_g    = (const float*)d_in[12];
    const float* bn_b    = (const float*)d_in[13];
    const float* bn_mean = (const float*)d_in[14];
    const float* bn_var  = (const float*)d_in[15];
    const float* c_w2    = (const float*)d_in[16];
    const float* c_b2    = (const float*)d_in[17];

    float* w = (float*)d_ws;
    float* h     = w + OFF_H;
    float* hT    = w + OFF_HT;
    float* a_i   = w + OFF_AI;
    float* a_jT  = w + OFF_AJT;
    float* sq    = w + OFF_SQ;
    float* h_agg = w + OFF_HAGG;
    float* h_res = w + OFF_HRES;
    float* out   = (float*)d_out;

    k1_embed<<<1024, 256, 0, stream>>>(x, proj_w, proj_b, s_w1, s_b1,
                                       h, hT, a_i, a_jT, sq);
    k2_pair<<<1024, 256, 0, stream>>>(a_i, a_jT, hT, h, sq,
                                      ln_g, ln_b, s_w2, s_b2, h_agg);
    k3_gnn<<<1024, 256, 0, stream>>>(h_agg, h, gnn_w, h_res);
    k4_pool_cls<<<16, 256, 0, stream>>>(h_res, c_w1, c_b1, bn_g, bn_b,
                                        bn_mean, bn_var, c_w2, c_b2, out);
}